// Round 1
// 18452.957 us; speedup vs baseline: 1.2481x; 1.2481x over previous
//
#include <hip/hip_runtime.h>
#include <math.h>

#define DIM 512
#define NSLOTS 32
#define BATCH 32
#define SEQT 2048
#define KSPLIT 8
#define SLICE 64   // DIM / KSPLIT
#define TPB 512    // 8 waves; no streaming waves needed anymore

#define SCOPE_AGENT __HIP_MEMORY_SCOPE_AGENT

// ============================================================================
// Kernel 1: X[m,o] = sum_k x_seq[m,k] * W_x[o,k] + b_h[o]  (into d_out h_seq)
// (unchanged from previous version — <1% of total time)
// ============================================================================
__global__ __launch_bounds__(256) void xw_gemm_kernel(
    const float* __restrict__ A,    // x_seq [M, 512]
    const float* __restrict__ Bm,   // W_x   [512, 512]
    const float* __restrict__ bias, // b_h [512]
    float* __restrict__ C)          // [M, 512]
{
    __shared__ __align__(16) float As[16][68];
    __shared__ __align__(16) float Bs[16][68];

    const int tid = threadIdx.x;
    const int tx = tid & 15, ty = tid >> 4;
    const int bm = blockIdx.x, bo = blockIdx.y;
    const int r = tid >> 2, c = tid & 3;

    float acc[4][4];
#pragma unroll
    for (int i = 0; i < 4; ++i)
#pragma unroll
        for (int j = 0; j < 4; ++j) acc[i][j] = 0.f;

    const float* Arow = A + (size_t)(bm * 64 + r) * DIM + c * 4;
    const float* Brow = Bm + (size_t)(bo * 64 + r) * DIM + c * 4;

    for (int kt = 0; kt < DIM / 16; ++kt) {
        float4 a4 = *(const float4*)(Arow + kt * 16);
        float4 b4 = *(const float4*)(Brow + kt * 16);
        As[c * 4 + 0][r] = a4.x; As[c * 4 + 1][r] = a4.y;
        As[c * 4 + 2][r] = a4.z; As[c * 4 + 3][r] = a4.w;
        Bs[c * 4 + 0][r] = b4.x; Bs[c * 4 + 1][r] = b4.y;
        Bs[c * 4 + 2][r] = b4.z; Bs[c * 4 + 3][r] = b4.w;
        __syncthreads();
#pragma unroll
        for (int kk = 0; kk < 16; ++kk) {
            float4 av = *(const float4*)&As[kk][ty * 4];
            float4 bv = *(const float4*)&Bs[kk][tx * 4];
            float a[4] = {av.x, av.y, av.z, av.w};
            float b[4] = {bv.x, bv.y, bv.z, bv.w};
#pragma unroll
            for (int i = 0; i < 4; ++i)
#pragma unroll
                for (int j = 0; j < 4; ++j)
                    acc[i][j] = fmaf(a[i], b[j], acc[i][j]);
        }
        __syncthreads();
    }

    const int col = bo * 64 + tx * 4;
    float4 bia = *(const float4*)(bias + col);
#pragma unroll
    for (int i = 0; i < 4; ++i) {
        float4 v = {acc[i][0] + bia.x, acc[i][1] + bia.y,
                    acc[i][2] + bia.z, acc[i][3] + bia.w};
        *(float4*)(C + (size_t)(bm * 64 + ty * 4 + i) * DIM + col) = v;
    }
}

// ============================================================================
// Entmax-1.5 over 32 slots, fully in-wave (unchanged, proven).
// Caller must invoke under `if (lane < 32)`; `sc` = score for slot == lane.
// ============================================================================
__device__ __forceinline__ float entmax_wave(float sc, int lane)
{
    float z = sc * 0.5f;
    float zmax = z;
#pragma unroll
    for (int off = 16; off >= 1; off >>= 1)
        zmax = fmaxf(zmax, __shfl_xor(zmax, off, 32));
    z -= zmax;
    int rank = 0;
#pragma unroll
    for (int j = 0; j < 32; ++j) {
        float zj = __shfl(z, j, 32);
        rank += (zj > z) || (zj == z && j < lane);
    }
    float zsv = __int_as_float(
        __builtin_amdgcn_ds_permute(rank << 2, __float_as_int(z)));
    float cs = zsv, css = zsv * zsv;
#pragma unroll
    for (int off = 1; off < 32; off <<= 1) {
        float a = __shfl_up(cs, off, 32);
        float b2 = __shfl_up(css, off, 32);
        if (lane >= off) { cs += a; css += b2; }
    }
    float kk = (float)(lane + 1);
    float mean = cs / kk, meansq = css / kk;
    float ss = kk * (meansq - mean * mean);
    float delta = fmaxf((1.0f - ss) / kk, 0.0f);
    float tau = mean - sqrtf(delta);
    unsigned long long ball = __ballot(tau <= zsv);
    int kstar = __popcll(ball & 0xFFFFFFFFull) - 1;
    float taustar = __shfl(tau, kstar, 32);
    float pp = fmaxf(z - taustar, 0.0f);
    return pp * pp;
}

union f2u { float2 f; unsigned long long u; };

// score phase: 16 lanes/slot, float4 over LDS; all WGs compute identically.
__device__ __forceinline__ void phase_scores(
    const float4* __restrict__ tp4s,   // tape row for slot s = tid>>4
    const float* __restrict__ vecF,    // work[] or wvec[] (LDS)
    float* __restrict__ scoresF, int s, int l)
{
    const float4* vv4 = (const float4*)vecF;
    float ax = 0.f, ay = 0.f, az = 0.f, aw = 0.f;
#pragma unroll
    for (int j = 0; j < 8; ++j) {
        int f = l + 16 * j;
        float4 tv = tp4s[f];
        float4 vv = vv4[f];
        ax = fmaf(tv.x, vv.x, ax); ay = fmaf(tv.y, vv.y, ay);
        az = fmaf(tv.z, vv.z, az); aw = fmaf(tv.w, vv.w, aw);
    }
    float acc = (ax + ay) + (az + aw);
    acc += __shfl_down(acc, 8, 16);
    acc += __shfl_down(acc, 4, 16);
    acc += __shfl_down(acc, 2, 16);
    acc += __shfl_down(acc, 1, 16);
    if (l == 0) scoresF[s] = acc * 0.044194173824159216f;  // 1/sqrt(512)
}

// tape(t-1) = tape(t-2)*(1-beta) + beta*wvec — float4, thread handles col q
// for the 8 slots of its group g. Same expression & order in every WG.
__device__ __forceinline__ void phase_tape_update(
    float4 (*tape4)[DIM / 4], const float* __restrict__ wvecF,
    const float* __restrict__ probF, int q, int g)
{
    float4 wv4 = ((const float4*)wvecF)[q];
#pragma unroll
    for (int i = 0; i < 8; ++i) {
        int n = g * 8 + i;
        float bb = probF[n];
        float4 tv = tape4[n][q];
        tv.x = tv.x * (1.0f - bb) + bb * wv4.x;
        tv.y = tv.y * (1.0f - bb) + bb * wv4.y;
        tv.z = tv.z * (1.0f - bb) + bb * wv4.z;
        tv.w = tv.w * (1.0f - bb) + bb * wv4.w;
        tape4[n][q] = tv;
    }
}

// both column-sliced matvec partials from the WG's 64-col slice of work;
// weights live in registers, work slice read as uniform broadcast from LDS.
__device__ __forceinline__ f2u colmv_partials(
    const float4* __restrict__ wk4,  // &work[k*SLICE] as float4*
    const float4* __restrict__ w1r, const float4* __restrict__ w2r)
{
    float m1p = 0.f, m2p = 0.f;
#pragma unroll
    for (int j = 0; j < 16; ++j) {
        float4 wv = wk4[j];
        m1p = fmaf(w1r[j].x, wv.x, m1p); m1p = fmaf(w1r[j].y, wv.y, m1p);
        m1p = fmaf(w1r[j].z, wv.z, m1p); m1p = fmaf(w1r[j].w, wv.w, m1p);
        m2p = fmaf(w2r[j].x, wv.x, m2p); m2p = fmaf(w2r[j].y, wv.y, m2p);
        m2p = fmaf(w2r[j].z, wv.z, m2p); m2p = fmaf(w2r[j].w, wv.w, m2p);
    }
    f2u v; v.f = make_float2(m1p, m2p);
    return v;
}

__device__ __forceinline__ void wg_sync(int* cnt_b, int target, int* deadflag,
                                        int tid)
{
    if (tid == 0 && !*deadflag) {
        __hip_atomic_fetch_add(cnt_b, 1, __ATOMIC_RELAXED, SCOPE_AGENT);
        int it = 0;
        while (__hip_atomic_load(cnt_b, __ATOMIC_RELAXED, SCOPE_AGENT) <
               target) {
            if (++it > (1 << 20)) { *deadflag = 1; break; }
            if (it > 8) __builtin_amdgcn_s_sleep(2);
        }
    }
    __syncthreads();
}

// ============================================================================
// Kernel 2: fused recurrence, register-resident weights.
//  - WG (b,k) holds W_h[:, k*64..] and W_write[:, k*64..] column slices in
//    VGPRs (128 regs/thread) — ZERO per-step weight streaming.
//  - Both matvecs are column-sliced: they need only the LOCAL work slice, so
//    mv1parts(t+1) and mv2parts(t) ride the SAME single exchange per step.
//  - Every WG computes the full work(t)/wvec(t)/tape(t) bitwise-identically
//    (fixed summation orders), so no wn broadcast is needed.
//  - parts parity double-buffered exactly as before: writes to buffer p at
//    step t+2 are gated by sync(t+1), program-ordered after all reads of
//    buffer p at step t. Agent-scope relaxed atomics; vmcnt(0) before add.
// ============================================================================
__global__ __launch_bounds__(TPB) void recurrent_kernel(
    const float* __restrict__ h_tape0,
    const float* __restrict__ h_work0,
    const float* __restrict__ W_h,
    const float* __restrict__ W_write,
    float* out,
    unsigned long long* parts,   // [2][BATCH][KSPLIT][DIM] packed float2
    int* cnt)                    // [BATCH][32]
{
    __shared__ __align__(16) float4 tape4[NSLOTS][DIM / 4];  // 64 KB
    __shared__ __align__(16) float work[DIM];
    __shared__ __align__(16) float wvec[DIM];
    __shared__ __align__(16) float rdaccF[4][DIM + 4];       // pad: bank-spread
    __shared__ float scores[NSLOTS];
    __shared__ float prob[NSLOTS];
    __shared__ int deadflag;

    const int tid = threadIdx.x;
    const int bid = blockIdx.x;
    const int k = bid & 7;
    const int b = bid >> 3;

    // ---- persistent register weights: row tid, cols k*64..k*64+63 ----
    float4 w1r[16], w2r[16];
    {
        const float4* Wh = (const float4*)(W_h + (size_t)tid * DIM + k * SLICE);
        const float4* Ww = (const float4*)(W_write + (size_t)tid * DIM + k * SLICE);
#pragma unroll
        for (int j = 0; j < 16; ++j) { w1r[j] = Wh[j]; w2r[j] = Ww[j]; }
    }

    float* tapeF = (float*)tape4;
    if (tid == 0) deadflag = 0;
    for (int i = tid; i < NSLOTS * DIM; i += TPB)
        tapeF[i] = h_tape0[(size_t)b * NSLOTS * DIM + i];
    work[tid] = h_work0[b * DIM + tid];
    __syncthreads();

    float* hseq_b = out + (size_t)b * SEQT * DIM;
    int* cnt_b = cnt + b * 32;

    const int s = tid >> 4, l = tid & 15;     // score-phase mapping
    const int q = tid & 127, g = tid >> 7;    // float4-col / slot-group mapping
    const float4* tp4s = tape4[s];

    float wn_v = work[tid];   // work(t-1)[tid]
    float m1v;                // W_h @ work(t-1), pre-summed, element tid

    // ---- prologue: exchange mv1parts for step 0 (pbuf = (t=-1)&1 = 1) ----
    {
        unsigned long long* pbx =
            parts + (size_t)(1 * BATCH + b) * (KSPLIT * DIM);
        f2u v = colmv_partials((const float4*)work + k * (SLICE / 4), w1r, w2r);
        __hip_atomic_store(&pbx[k * DIM + tid], v.u, __ATOMIC_RELAXED,
                           SCOPE_AGENT);
        asm volatile("s_waitcnt vmcnt(0)" ::: "memory");
        __syncthreads();
        wg_sync(cnt_b, KSPLIT, &deadflag, tid);
        float m1n = 0.f;
#pragma unroll
        for (int j = 0; j < KSPLIT; ++j) {
            f2u v2;
            v2.u = __hip_atomic_load(&pbx[j * DIM + tid], __ATOMIC_RELAXED,
                                     SCOPE_AGENT);
            m1n += v2.f.x;
        }
        m1v = m1n;
    }

    for (int t = 0; t < SEQT; ++t) {
        const int pbuf = t & 1;
        unsigned long long* pb =
            parts + (size_t)(pbuf * BATCH + b) * (KSPLIT * DIM);

        // prefetch x(t) early (L2/LLC latency hides under phases A-F)
        float xv = hseq_b[(size_t)t * DIM + tid];

        // A: write-scores(t-1) = tape(t-2) . wvec(t-1)
        if (t > 0) phase_scores(tp4s, wvec, scores, s, l);
        __syncthreads();

        // B: entmax(write) -> beta
        if (t > 0 && tid < 32) prob[tid] = entmax_wave(scores[tid], tid);
        __syncthreads();

        // C: tape(t-1) update + publish h_seq(t-1) (after sync(t-1): safe
        //    vs all WGs' reads of X[t-1])
        if (t > 0) {
            phase_tape_update(tape4, wvec, prob, q, g);
            if ((tid >> 6) == k) hseq_b[(size_t)(t - 1) * DIM + tid] = wn_v;
        }
        __syncthreads();

        // D: read-scores(t) = tape(t-1) . work(t-1)
        phase_scores(tp4s, work, scores, s, l);
        __syncthreads();

        // E: entmax(read) -> alpha
        if (tid < 32) prob[tid] = entmax_wave(scores[tid], tid);
        __syncthreads();

        // F: readv partials: rdacc[g][:] = sum_{n in group g} alpha[n]*tape[n]
        {
            float4 r = make_float4(0.f, 0.f, 0.f, 0.f);
#pragma unroll
            for (int i = 0; i < 8; ++i) {
                int n = g * 8 + i;
                float an = prob[n];
                float4 tv = tape4[n][q];
                r.x = fmaf(an, tv.x, r.x); r.y = fmaf(an, tv.y, r.y);
                r.z = fmaf(an, tv.z, r.z); r.w = fmaf(an, tv.w, r.w);
            }
            ((float4*)rdaccF[g])[q] = r;
        }
        __syncthreads();

        // G: combine readv + tanh -> work(t) (identical in every WG)
        {
            float rv = ((rdaccF[0][tid] + rdaccF[1][tid]) + rdaccF[2][tid]) +
                       rdaccF[3][tid];
            wn_v = tanhf(m1v + xv + rv);     // b_h folded into X by the GEMM
            work[tid] = wn_v;                // work(t-1) dead after phase D
        }
        __syncthreads();

        // H: column matvec partials (mv1 for t+1, mv2 for t) + publish
        {
            f2u v = colmv_partials((const float4*)work + k * (SLICE / 4),
                                   w1r, w2r);
            __hip_atomic_store(&pb[k * DIM + tid], v.u, __ATOMIC_RELAXED,
                               SCOPE_AGENT);
        }
        asm volatile("s_waitcnt vmcnt(0)" ::: "memory");
        __syncthreads();

        // I: single cross-WG sync per step (prologue added 1 -> target t+2)
        wg_sync(cnt_b, (t + 2) * KSPLIT, &deadflag, tid);

        // J: gather — fixed order j=0..7 keeps all WGs bitwise identical
        {
            float m1n = 0.f, wvn = 0.f;
#pragma unroll
            for (int j = 0; j < KSPLIT; ++j) {
                f2u v2;
                v2.u = __hip_atomic_load(&pb[j * DIM + tid], __ATOMIC_RELAXED,
                                         SCOPE_AGENT);
                m1n += v2.f.x;
                wvn += v2.f.y;
            }
            m1v = m1n;
            wvec[tid] = wvn;
        }
        __syncthreads();
    }

    // ---- final tail: write-scores(T-1), entmax, tape-update(T-1) ----
    phase_scores(tp4s, wvec, scores, s, l);
    __syncthreads();
    if (tid < 32) prob[tid] = entmax_wave(scores[tid], tid);
    __syncthreads();
    phase_tape_update(tape4, wvec, prob, q, g);
    if ((tid >> 6) == k) hseq_b[(size_t)(SEQT - 1) * DIM + tid] = wn_v;
    __syncthreads();

    // epilogue: WG k writes tape slots [k*4,(k+1)*4) and its h_last slice
    const size_t tape_off =
        (size_t)BATCH * SEQT * DIM + (size_t)b * NSLOTS * DIM;
    for (int i = tid; i < 4 * DIM; i += TPB)
        out[tape_off + (size_t)k * 4 * DIM + i] = tapeF[k * 4 * DIM + i];
    if ((tid >> 6) == k)
        out[(size_t)BATCH * SEQT * DIM + (size_t)BATCH * NSLOTS * DIM +
            (size_t)b * DIM + tid] = wn_v;
}

// ============================================================================
extern "C" void kernel_launch(void* const* d_in, const int* in_sizes, int n_in,
                              void* d_out, int out_size, void* d_ws,
                              size_t ws_size, hipStream_t stream)
{
    const float* x_seq   = (const float*)d_in[0];
    const float* h_tape  = (const float*)d_in[1];
    const float* h_work  = (const float*)d_in[2];
    const float* W_h     = (const float*)d_in[3];
    const float* W_x     = (const float*)d_in[4];
    const float* b_h     = (const float*)d_in[5];
    const float* W_write = (const float*)d_in[6];
    float* out = (float*)d_out;

    unsigned long long* parts = (unsigned long long*)d_ws;  // 2 MB
    int* cnt = (int*)(parts + 2 * BATCH * KSPLIT * DIM);    // 4 KB

    hipMemsetAsync(cnt, 0, BATCH * 32 * sizeof(int), stream);

    dim3 g1((BATCH * SEQT) / 64, DIM / 64);
    xw_gemm_kernel<<<g1, 256, 0, stream>>>(x_seq, W_x, b_h, out);

    recurrent_kernel<<<BATCH * KSPLIT, TPB, 0, stream>>>(
        h_tape, h_work, W_h, W_write, out, parts, cnt);
}

// Round 2
// 16441.084 us; speedup vs baseline: 1.4009x; 1.1224x over previous
//
#include <hip/hip_runtime.h>
#include <math.h>

#define DIM 512
#define NSLOTS 32
#define BATCH 32
#define SEQT 2048
#define KSPLIT 8
#define SLICE 64    // DIM / KSPLIT
#define TPB 512
#define TPAD 68     // tape row pad (floats) to spread LDS banks

#define SCOPE_AGENT __HIP_MEMORY_SCOPE_AGENT

// ============================================================================
// Kernel 1: X[m,o] = sum_k x_seq[m,k] * W_x[o,k] + b_h[o]  (into d_out h_seq)
// (unchanged — <3% of total time)
// ============================================================================
__global__ __launch_bounds__(256) void xw_gemm_kernel(
    const float* __restrict__ A,    // x_seq [M, 512]
    const float* __restrict__ Bm,   // W_x   [512, 512]
    const float* __restrict__ bias, // b_h [512]
    float* __restrict__ C)          // [M, 512]
{
    __shared__ __align__(16) float As[16][68];
    __shared__ __align__(16) float Bs[16][68];

    const int tid = threadIdx.x;
    const int tx = tid & 15, ty = tid >> 4;
    const int bm = blockIdx.x, bo = blockIdx.y;
    const int r = tid >> 2, c = tid & 3;

    float acc[4][4];
#pragma unroll
    for (int i = 0; i < 4; ++i)
#pragma unroll
        for (int j = 0; j < 4; ++j) acc[i][j] = 0.f;

    const float* Arow = A + (size_t)(bm * 64 + r) * DIM + c * 4;
    const float* Brow = Bm + (size_t)(bo * 64 + r) * DIM + c * 4;

    for (int kt = 0; kt < DIM / 16; ++kt) {
        float4 a4 = *(const float4*)(Arow + kt * 16);
        float4 b4 = *(const float4*)(Brow + kt * 16);
        As[c * 4 + 0][r] = a4.x; As[c * 4 + 1][r] = a4.y;
        As[c * 4 + 2][r] = a4.z; As[c * 4 + 3][r] = a4.w;
        Bs[c * 4 + 0][r] = b4.x; Bs[c * 4 + 1][r] = b4.y;
        Bs[c * 4 + 2][r] = b4.z; Bs[c * 4 + 3][r] = b4.w;
        __syncthreads();
#pragma unroll
        for (int kk = 0; kk < 16; ++kk) {
            float4 av = *(const float4*)&As[kk][ty * 4];
            float4 bv = *(const float4*)&Bs[kk][tx * 4];
            float a[4] = {av.x, av.y, av.z, av.w};
            float b[4] = {bv.x, bv.y, bv.z, bv.w};
#pragma unroll
            for (int i = 0; i < 4; ++i)
#pragma unroll
                for (int j = 0; j < 4; ++j)
                    acc[i][j] = fmaf(a[i], b[j], acc[i][j]);
        }
        __syncthreads();
    }

    const int col = bo * 64 + tx * 4;
    float4 bia = *(const float4*)(bias + col);
#pragma unroll
    for (int i = 0; i < 4; ++i) {
        float4 v = {acc[i][0] + bia.x, acc[i][1] + bia.y,
                    acc[i][2] + bia.z, acc[i][3] + bia.w};
        *(float4*)(C + (size_t)(bm * 64 + ty * 4 + i) * DIM + col) = v;
    }
}

// ============================================================================
// Entmax-1.5 over 32 slots, fully in-wave (unchanged, proven).
// Caller must invoke under `if (lane < 32)`; `sc` = score for slot == lane.
// ============================================================================
__device__ __forceinline__ float entmax_wave(float sc, int lane)
{
    float z = sc * 0.5f;
    float zmax = z;
#pragma unroll
    for (int off = 16; off >= 1; off >>= 1)
        zmax = fmaxf(zmax, __shfl_xor(zmax, off, 32));
    z -= zmax;
    int rank = 0;
#pragma unroll
    for (int j = 0; j < 32; ++j) {
        float zj = __shfl(z, j, 32);
        rank += (zj > z) || (zj == z && j < lane);
    }
    float zsv = __int_as_float(
        __builtin_amdgcn_ds_permute(rank << 2, __float_as_int(z)));
    float cs = zsv, css = zsv * zsv;
#pragma unroll
    for (int off = 1; off < 32; off <<= 1) {
        float a = __shfl_up(cs, off, 32);
        float b2 = __shfl_up(css, off, 32);
        if (lane >= off) { cs += a; css += b2; }
    }
    float kk = (float)(lane + 1);
    float mean = cs / kk, meansq = css / kk;
    float ss = kk * (meansq - mean * mean);
    float delta = fmaxf((1.0f - ss) / kk, 0.0f);
    float tau = mean - sqrtf(delta);
    unsigned long long ball = __ballot(tau <= zsv);
    int kstar = __popcll(ball & 0xFFFFFFFFull) - 1;
    float taustar = __shfl(tau, kstar, 32);
    float pp = fmaxf(z - taustar, 0.0f);
    return pp * pp;
}

union f2u { float2 f; unsigned long long u; };

__device__ __forceinline__ void wg_sync(int* cnt_b, int target, int* deadflag,
                                        int tid)
{
    if (tid == 0 && !*deadflag) {
        __hip_atomic_fetch_add(cnt_b, 1, __ATOMIC_RELAXED, SCOPE_AGENT);
        int it = 0;
        while (__hip_atomic_load(cnt_b, __ATOMIC_RELAXED, SCOPE_AGENT) <
               target) {
            if (++it > (1 << 20)) { *deadflag = 1; break; }
            if (it > 8) __builtin_amdgcn_s_sleep(2);
        }
    }
    __syncthreads();
}

// ============================================================================
// Kernel 2: fused recurrence, fully column-sharded.
//  - WG (b,k) owns cols [64k,64k+64) of tape (8.7 KB LDS), work, wvec, x.
//    Weight column slices (W_h, W_write rows x own cols) stay in VGPRs.
//  - Two LLC exchanges per step via one counter (targets (2t+2)K, (2t+3)K):
//    EX-A: score partials u_k[n]=tape.wvec, v_k[n]=tape.work, s_k=wvec.work
//          (33 f2 per WG). Read-scores on the updated tape reconstructed as
//          r[n] = ((1-beta_n) v[n] + beta_n s) / sqrt(d)  — exact algebra,
//          different rounding (bounded by contractive recurrence).
//    EX-w: matvec row partials (as before); gather only OWN 64-row slice.
//  - Single-buffered exchanges: each WG's reads of a buffer at step t are
//    program-ordered before its increment of the NEXT sync, which gates the
//    next overwrite. Agent-scope relaxed atomics; vmcnt(0) before adds.
// ============================================================================
__global__ __launch_bounds__(TPB) void recurrent_kernel(
    const float* __restrict__ h_tape0,
    const float* __restrict__ h_work0,
    const float* __restrict__ W_h,
    const float* __restrict__ W_write,
    float* out,
    unsigned long long* partsM,  // [BATCH][KSPLIT][DIM]  (m1, m2) packed
    unsigned long long* partsA,  // [BATCH][KSPLIT][33]   (u, v) + (s, 0)
    int* cnt)                    // [BATCH][32]
{
    __shared__ __align__(16) float tape[NSLOTS][TPAD];  // 8704 B
    __shared__ __align__(16) float wkF[SLICE];   // work(t)[own cols]
    __shared__ __align__(16) float wvF[SLICE];   // wvec(t-1)[own cols]
    __shared__ __align__(16) float m1F[SLICE];   // (W_h @ work_t)[own cols]
    __shared__ __align__(16) float2 probBA[NSLOTS];  // (beta, alpha)
    __shared__ int deadflag;

    const int tid = threadIdx.x;
    const int bid = blockIdx.x;
    const int k = bid & 7;
    const int b = bid >> 3;
    const float inv_sqrt_d = 0.044194173824159216f;  // 1/sqrt(512)

    // persistent register weights: row tid, cols k*64..k*64+63
    float4 w1r[16], w2r[16];
    {
        const float4* Wh = (const float4*)(W_h + (size_t)tid * DIM + k * SLICE);
        const float4* Ww = (const float4*)(W_write + (size_t)tid * DIM + k * SLICE);
#pragma unroll
        for (int j = 0; j < 16; ++j) { w1r[j] = Wh[j]; w2r[j] = Ww[j]; }
    }

    if (tid == 0) deadflag = 0;
    {
        const int n = tid >> 4, c4 = tid & 15;
        float4 tv = *(const float4*)(h_tape0 +
            ((size_t)(b * NSLOTS + n)) * DIM + k * SLICE + 4 * c4);
        *(float4*)&tape[n][4 * c4] = tv;
    }
    if (tid < SLICE) {
        wkF[tid] = h_work0[b * DIM + k * SLICE + tid];
        wvF[tid] = 0.f;
        m1F[tid] = 0.f;
    }
    __syncthreads();

    float* hseq_b = out + (size_t)b * SEQT * DIM;
    int* cnt_b = cnt + b * 32;
    unsigned long long* pM = partsM + (size_t)b * KSPLIT * DIM;
    unsigned long long* pA = partsA + (size_t)b * KSPLIT * 33;

    // ---- prologue: matvec partials on work_0; sync #1; gather own slice ----
    {
        const float4* wk4 = (const float4*)wkF;
        float m1 = 0.f, m2 = 0.f;
#pragma unroll
        for (int j = 0; j < 16; ++j) {
            float4 wv = wk4[j];
            m1 = fmaf(w1r[j].x, wv.x, m1); m1 = fmaf(w1r[j].y, wv.y, m1);
            m1 = fmaf(w1r[j].z, wv.z, m1); m1 = fmaf(w1r[j].w, wv.w, m1);
            m2 = fmaf(w2r[j].x, wv.x, m2); m2 = fmaf(w2r[j].y, wv.y, m2);
            m2 = fmaf(w2r[j].z, wv.z, m2); m2 = fmaf(w2r[j].w, wv.w, m2);
        }
        f2u v; v.f = make_float2(m1, m2);
        __hip_atomic_store(&pM[k * DIM + tid], v.u, __ATOMIC_RELAXED,
                           SCOPE_AGENT);
        asm volatile("s_waitcnt vmcnt(0)" ::: "memory");
        __syncthreads();
        wg_sync(cnt_b, KSPLIT, &deadflag, tid);
        if (tid < SLICE) {
            float a1 = 0.f, a2 = 0.f;
#pragma unroll
            for (int j = 0; j < KSPLIT; ++j) {
                f2u v2;
                v2.u = __hip_atomic_load(&pM[j * DIM + k * SLICE + tid],
                                         __ATOMIC_RELAXED, SCOPE_AGENT);
                a1 += v2.f.x; a2 += v2.f.y;
            }
            m1F[tid] = a1;   // (W_h @ work_0)[own]
            wvF[tid] = a2;   // (W_write @ work_0)[own] — dead at t=0 (beta=0)
        }
        __syncthreads();
    }

    for (int t = 0; t < SEQT; ++t) {
        // x(t) prefetch by the readv-owner lanes (read-before-overwrite of
        // hseq[t], same thread, same cols — no cross-WG hazard)
        float xv = 0.f;
        if ((tid & 7) == 0)
            xv = hseq_b[(size_t)t * DIM + k * SLICE + (tid >> 3)];

        // B1: score partials u,v (16 lanes/slot, 4 cols each) + s (wave 0)
        {
            const int s = tid >> 4, l = tid & 15;
            float4 tv = *(const float4*)&tape[s][4 * l];
            float4 wv = *(const float4*)&wvF[4 * l];
            float4 wk = *(const float4*)&wkF[4 * l];
            float up = tv.x * wv.x;
            up = fmaf(tv.y, wv.y, up); up = fmaf(tv.z, wv.z, up);
            up = fmaf(tv.w, wv.w, up);
            float vp = tv.x * wk.x;
            vp = fmaf(tv.y, wk.y, vp); vp = fmaf(tv.z, wk.z, vp);
            vp = fmaf(tv.w, wk.w, vp);
#pragma unroll
            for (int off = 8; off >= 1; off >>= 1) {
                up += __shfl_down(up, off, 16);
                vp += __shfl_down(vp, off, 16);
            }
            if (l == 0) {
                f2u v; v.f = make_float2(up, vp);
                __hip_atomic_store(&pA[k * 33 + s], v.u, __ATOMIC_RELAXED,
                                   SCOPE_AGENT);
            }
            if (tid < 16) {
                float4 a = *(const float4*)&wvF[4 * tid];
                float4 b4 = *(const float4*)&wkF[4 * tid];
                float sp = a.x * b4.x;
                sp = fmaf(a.y, b4.y, sp); sp = fmaf(a.z, b4.z, sp);
                sp = fmaf(a.w, b4.w, sp);
#pragma unroll
                for (int off = 8; off >= 1; off >>= 1)
                    sp += __shfl_down(sp, off, 16);
                if (tid == 0) {
                    f2u v; v.f = make_float2(sp, 0.f);
                    __hip_atomic_store(&pA[k * 33 + 32], v.u, __ATOMIC_RELAXED,
                                       SCOPE_AGENT);
                }
            }
        }
        asm volatile("s_waitcnt vmcnt(0)" ::: "memory");
        __syncthreads();
        wg_sync(cnt_b, (2 * t + 2) * KSPLIT, &deadflag, tid);

        // B3: wave 0 gathers u,v,s; beta = entmax(u); r = (1-b)v + b*s;
        //     alpha = entmax(r)
        if (tid < 64) {
            float uu = 0.f, vv = 0.f;
            if (tid < 33) {
#pragma unroll
                for (int j = 0; j < KSPLIT; ++j) {
                    f2u v2;
                    v2.u = __hip_atomic_load(&pA[j * 33 + tid],
                                             __ATOMIC_RELAXED, SCOPE_AGENT);
                    uu += v2.f.x; vv += v2.f.y;
                }
            }
            float sfull = __shfl(uu, 32);   // lane 32 holds sum of s_k
            if (tid < 32) {
                float beta = 0.f;
                if (t > 0) beta = entmax_wave(uu * inv_sqrt_d, tid);
                float rr = ((1.0f - beta) * vv + beta * sfull) * inv_sqrt_d;
                float alpha = entmax_wave(rr, tid);
                probBA[tid] = make_float2(beta, alpha);
            }
        }
        __syncthreads();

        // B4: tape update (own cols), skip beta==0 slots (bit-exact skip)
        {
            const int n = tid >> 4, c4 = tid & 15;
            float bb = probBA[n].x;
            if (bb != 0.f) {
                float4 tv = *(const float4*)&tape[n][4 * c4];
                float4 wv = *(const float4*)&wvF[4 * c4];
                tv.x = tv.x * (1.0f - bb) + bb * wv.x;
                tv.y = tv.y * (1.0f - bb) + bb * wv.y;
                tv.z = tv.z * (1.0f - bb) + bb * wv.z;
                tv.w = tv.w * (1.0f - bb) + bb * wv.w;
                *(float4*)&tape[n][4 * c4] = tv;
            }
        }
        __syncthreads();

        // B5: readv (8 lanes/col) + tanh + work/h_seq write by owner lane
        {
            const int c = tid >> 3, j = tid & 7;
            float p = 0.f;
#pragma unroll
            for (int i = 0; i < 4; ++i) {
                int n = 4 * j + i;
                p = fmaf(probBA[n].y, tape[n][c], p);
            }
            p += __shfl_down(p, 4, 8);
            p += __shfl_down(p, 2, 8);
            p += __shfl_down(p, 1, 8);
            if (j == 0) {
                float wn = tanhf(m1F[c] + xv + p);
                wkF[c] = wn;
                hseq_b[(size_t)t * DIM + k * SLICE + c] = wn;
            }
        }
        __syncthreads();

        // B6: matvec partials on work_{t+1}; publish
        {
            const float4* wk4 = (const float4*)wkF;
            float m1 = 0.f, m2 = 0.f;
#pragma unroll
            for (int j = 0; j < 16; ++j) {
                float4 wv = wk4[j];
                m1 = fmaf(w1r[j].x, wv.x, m1); m1 = fmaf(w1r[j].y, wv.y, m1);
                m1 = fmaf(w1r[j].z, wv.z, m1); m1 = fmaf(w1r[j].w, wv.w, m1);
                m2 = fmaf(w2r[j].x, wv.x, m2); m2 = fmaf(w2r[j].y, wv.y, m2);
                m2 = fmaf(w2r[j].z, wv.z, m2); m2 = fmaf(w2r[j].w, wv.w, m2);
            }
            f2u v; v.f = make_float2(m1, m2);
            __hip_atomic_store(&pM[k * DIM + tid], v.u, __ATOMIC_RELAXED,
                               SCOPE_AGENT);
        }
        asm volatile("s_waitcnt vmcnt(0)" ::: "memory");
        __syncthreads();
        wg_sync(cnt_b, (2 * t + 3) * KSPLIT, &deadflag, tid);

        // B8: gather OWN 64-row slice only (8 loads per lane, j-order)
        if (tid < SLICE) {
            float a1 = 0.f, a2 = 0.f;
#pragma unroll
            for (int j = 0; j < KSPLIT; ++j) {
                f2u v2;
                v2.u = __hip_atomic_load(&pM[j * DIM + k * SLICE + tid],
                                         __ATOMIC_RELAXED, SCOPE_AGENT);
                a1 += v2.f.x; a2 += v2.f.y;
            }
            m1F[tid] = a1;   // (W_h @ work_{t+1})[own]
            wvF[tid] = a2;   // wvec(t) = (W_write @ work_{t+1})[own]
        }
        __syncthreads();
    }

    // ---- epilogue: beta(T-1) and final tape update ----
    {
        const int s = tid >> 4, l = tid & 15;
        float4 tv = *(const float4*)&tape[s][4 * l];
        float4 wv = *(const float4*)&wvF[4 * l];
        float up = tv.x * wv.x;
        up = fmaf(tv.y, wv.y, up); up = fmaf(tv.z, wv.z, up);
        up = fmaf(tv.w, wv.w, up);
#pragma unroll
        for (int off = 8; off >= 1; off >>= 1)
            up += __shfl_down(up, off, 16);
        if (l == 0) {
            f2u v; v.f = make_float2(up, 0.f);
            __hip_atomic_store(&pA[k * 33 + s], v.u, __ATOMIC_RELAXED,
                               SCOPE_AGENT);
        }
    }
    asm volatile("s_waitcnt vmcnt(0)" ::: "memory");
    __syncthreads();
    wg_sync(cnt_b, (2 * SEQT + 2) * KSPLIT, &deadflag, tid);
    if (tid < 32) {
        float uu = 0.f;
#pragma unroll
        for (int j = 0; j < KSPLIT; ++j) {
            f2u v2;
            v2.u = __hip_atomic_load(&pA[j * 33 + tid], __ATOMIC_RELAXED,
                                     SCOPE_AGENT);
            uu += v2.f.x;
        }
        float beta = entmax_wave(uu * inv_sqrt_d, tid);
        probBA[tid] = make_float2(beta, 0.f);
    }
    __syncthreads();
    {
        const int n = tid >> 4, c4 = tid & 15;
        float bb = probBA[n].x;
        if (bb != 0.f) {
            float4 tv = *(const float4*)&tape[n][4 * c4];
            float4 wv = *(const float4*)&wvF[4 * c4];
            tv.x = tv.x * (1.0f - bb) + bb * wv.x;
            tv.y = tv.y * (1.0f - bb) + bb * wv.y;
            tv.z = tv.z * (1.0f - bb) + bb * wv.z;
            tv.w = tv.w * (1.0f - bb) + bb * wv.w;
            *(float4*)&tape[n][4 * c4] = tv;
        }
    }
    __syncthreads();

    // outputs: tape_final own col-slice + h_last own slice
    {
        const int n = tid >> 4, c4 = tid & 15;
        float4 tv = *(const float4*)&tape[n][4 * c4];
        *(float4*)(out + (size_t)BATCH * SEQT * DIM +
                   ((size_t)(b * NSLOTS + n)) * DIM + k * SLICE + 4 * c4) = tv;
    }
    if (tid < SLICE)
        out[(size_t)BATCH * SEQT * DIM + (size_t)BATCH * NSLOTS * DIM +
            (size_t)b * DIM + k * SLICE + tid] = wkF[tid];
}

// ============================================================================
extern "C" void kernel_launch(void* const* d_in, const int* in_sizes, int n_in,
                              void* d_out, int out_size, void* d_ws,
                              size_t ws_size, hipStream_t stream)
{
    const float* x_seq   = (const float*)d_in[0];
    const float* h_tape  = (const float*)d_in[1];
    const float* h_work  = (const float*)d_in[2];
    const float* W_h     = (const float*)d_in[3];
    const float* W_x     = (const float*)d_in[4];
    const float* b_h     = (const float*)d_in[5];
    const float* W_write = (const float*)d_in[6];
    float* out = (float*)d_out;

    unsigned long long* partsM = (unsigned long long*)d_ws;          // 1 MB
    unsigned long long* partsA = partsM + (size_t)BATCH * KSPLIT * DIM;  // 66 KB
    int* cnt = (int*)(partsA + (size_t)BATCH * KSPLIT * 33);         // 4 KB

    hipMemsetAsync(cnt, 0, BATCH * 32 * sizeof(int), stream);

    dim3 g1((BATCH * SEQT) / 64, DIM / 64);
    xw_gemm_kernel<<<g1, 256, 0, stream>>>(x_seq, W_x, b_h, out);

    recurrent_kernel<<<BATCH * KSPLIT, TPB, 0, stream>>>(
        h_tape, h_work, W_h, W_write, out, partsM, partsA, cnt);
}

// Round 3
// 14365.724 us; speedup vs baseline: 1.6032x; 1.1445x over previous
//
#include <hip/hip_runtime.h>
#include <math.h>

#define DIM 512
#define NSLOTS 32
#define BATCH 32
#define SEQT 2048
#define KSPLIT 8
#define SLICE 64    // DIM / KSPLIT
#define TPB 512

#define SCOPE_AGENT __HIP_MEMORY_SCOPE_AGENT
#define SCOPE_WG    __HIP_MEMORY_SCOPE_WORKGROUP

// ============================================================================
// Kernel 1: X[m,o] = sum_k x_seq[m,k] * W_x[o,k] + b_h[o]  (into d_out h_seq)
// ============================================================================
__global__ __launch_bounds__(256) void xw_gemm_kernel(
    const float* __restrict__ A,    // x_seq [M, 512]
    const float* __restrict__ Bm,   // W_x   [512, 512]
    const float* __restrict__ bias, // b_h [512]
    float* __restrict__ C)          // [M, 512]
{
    __shared__ __align__(16) float As[16][68];
    __shared__ __align__(16) float Bs[16][68];

    const int tid = threadIdx.x;
    const int tx = tid & 15, ty = tid >> 4;
    const int bm = blockIdx.x, bo = blockIdx.y;
    const int r = tid >> 2, c = tid & 3;

    float acc[4][4];
#pragma unroll
    for (int i = 0; i < 4; ++i)
#pragma unroll
        for (int j = 0; j < 4; ++j) acc[i][j] = 0.f;

    const float* Arow = A + (size_t)(bm * 64 + r) * DIM + c * 4;
    const float* Brow = Bm + (size_t)(bo * 64 + r) * DIM + c * 4;

    for (int kt = 0; kt < DIM / 16; ++kt) {
        float4 a4 = *(const float4*)(Arow + kt * 16);
        float4 b4 = *(const float4*)(Brow + kt * 16);
        As[c * 4 + 0][r] = a4.x; As[c * 4 + 1][r] = a4.y;
        As[c * 4 + 2][r] = a4.z; As[c * 4 + 3][r] = a4.w;
        Bs[c * 4 + 0][r] = b4.x; Bs[c * 4 + 1][r] = b4.y;
        Bs[c * 4 + 2][r] = b4.z; Bs[c * 4 + 3][r] = b4.w;
        __syncthreads();
#pragma unroll
        for (int kk = 0; kk < 16; ++kk) {
            float4 av = *(const float4*)&As[kk][ty * 4];
            float4 bv = *(const float4*)&Bs[kk][tx * 4];
            float a[4] = {av.x, av.y, av.z, av.w};
            float b[4] = {bv.x, bv.y, bv.z, bv.w};
#pragma unroll
            for (int i = 0; i < 4; ++i)
#pragma unroll
                for (int j = 0; j < 4; ++j)
                    acc[i][j] = fmaf(a[i], b[j], acc[i][j]);
        }
        __syncthreads();
    }

    const int col = bo * 64 + tx * 4;
    float4 bia = *(const float4*)(bias + col);
#pragma unroll
    for (int i = 0; i < 4; ++i) {
        float4 v = {acc[i][0] + bia.x, acc[i][1] + bia.y,
                    acc[i][2] + bia.z, acc[i][3] + bia.w};
        *(float4*)(C + (size_t)(bm * 64 + ty * 4 + i) * DIM + col) = v;
    }
}

// ============================================================================
// Entmax-1.5 over 32 slots using all 64 lanes of a wave.
// Input: lanes 0-31 hold sc for slot==lane (hi lanes ignored).
// Output: valid on lanes 0-31. Rank loop split across half-waves (16 iters).
// ============================================================================
__device__ __forceinline__ float entmax64(float sc, int lane)
{
    const int slot = lane & 31;
    float z = __shfl(sc, slot, 64) * 0.5f;   // replicate lo half to hi half
    float zmax = z;
#pragma unroll
    for (int off = 16; off >= 1; off >>= 1)
        zmax = fmaxf(zmax, __shfl_xor(zmax, off, 64));
    z -= zmax;
    const int jbase = (lane & 32) >> 1;      // lo lanes: j in [0,16); hi: [16,32)
    int rank = 0;
#pragma unroll
    for (int j = 0; j < 16; ++j) {
        int jj = jbase + j;
        float zj = __shfl(z, jj, 64);
        rank += (zj > z) || (zj == z && jj < slot);
    }
    rank += __shfl_xor(rank, 32, 64);
    float pp = 0.f;
    if (lane < 32) {
        float zsv = __int_as_float(
            __builtin_amdgcn_ds_permute(rank << 2, __float_as_int(z)));
        float cs = zsv, css = zsv * zsv;
#pragma unroll
        for (int off = 1; off < 32; off <<= 1) {
            float a = __shfl_up(cs, off, 32);
            float b2 = __shfl_up(css, off, 32);
            if (lane >= off) { cs += a; css += b2; }
        }
        float kk = (float)(lane + 1);
        float mean = cs / kk, meansq = css / kk;
        float ss = kk * (meansq - mean * mean);
        float delta = fmaxf((1.0f - ss) / kk, 0.0f);
        float tau = mean - sqrtf(delta);
        unsigned long long ball = __ballot(tau <= zsv);
        int kstar = __popcll(ball & 0xFFFFFFFFull) - 1;
        float taustar = __shfl(tau, kstar, 32);
        pp = fmaxf(z - taustar, 0.0f);
        pp = pp * pp;
    }
    return pp;
}

union f2u { float2 f; unsigned long long u; };

// Dataflow sync: lanes 0-7 poll per-WG tags until >= target. No counter,
// no extra hop. Timeout sets deadflag (kernel completes with garbage
// instead of hanging). Compiler memory barrier stops gather hoisting.
__device__ __forceinline__ void poll8(int* tags, int target, int* dead,
                                      int lane)
{
    bool d = __hip_atomic_load(dead, __ATOMIC_RELAXED, SCOPE_WG) != 0;
    if (lane < KSPLIT && !d) {
        int it = 0;
        while (__hip_atomic_load(&tags[lane], __ATOMIC_RELAXED, SCOPE_AGENT) <
               target) {
            if (++it > (1 << 20)) {
                __hip_atomic_store(dead, 1, __ATOMIC_RELAXED, SCOPE_WG);
                break;
            }
            __builtin_amdgcn_s_sleep(1);
        }
    }
    asm volatile("" ::: "memory");
}

// ============================================================================
// Kernel 2: fused recurrence, column-sharded, tag-dataflow synced.
//  - WG (b,k) owns cols [64k,64k+64): tape_t[col][slot] (stride 33 -> all
//    tape phases <=2-way bank aliasing, i.e. free), work/wvec/m1 slices.
//    Weight column slices in VGPRs.
//  - EX-A (u,v,s score partials): computed, published, tagged, polled and
//    gathered ENTIRELY by wave 0 (no barrier, own-wave vmcnt drain only).
//    r_scores reconstructed as ((1-beta)v + beta*s)/sqrt(d) (exact algebra).
//  - EX-M (matvec partials): all threads publish, drain, barrier, tag;
//    wave 0 polls+gathers own 64-row slice.
//  - Single-buffered pA/pM are race-free by induction: publishing step t+1
//    requires having gathered step t from ALL peers, which proves every
//    peer finished reading the buffer being overwritten.
//  - 3 barriers per step (was 8).
// ============================================================================
__global__ __launch_bounds__(TPB) void recurrent_kernel(
    const float* __restrict__ h_tape0,
    const float* __restrict__ h_work0,
    const float* __restrict__ W_h,
    const float* __restrict__ W_write,
    float* out,
    unsigned long long* partsM,  // [BATCH][KSPLIT][DIM]  (m1, m2) packed
    unsigned long long* partsA,  // [BATCH][KSPLIT][33]   (u, v) + (s, 0)
    int* tagA,                   // [BATCH][32] (128B/batch)
    int* tagM)                   // [BATCH][32]
{
    __shared__ __align__(16) float tape_t[SLICE][NSLOTS + 1];  // [64][33]
    __shared__ __align__(16) float wkF[SLICE];   // work(t)[own cols]
    __shared__ __align__(16) float wvF[SLICE];   // wvec(t-1)[own cols]
    __shared__ __align__(16) float m1F[SLICE];   // (W_h @ work_t)[own cols]
    __shared__ __align__(16) float2 probBA[NSLOTS];  // (beta, alpha)
    __shared__ int deadflag;

    const int tid = threadIdx.x;
    const int bid = blockIdx.x;
    const int k = bid & 7;
    const int b = bid >> 3;
    const float inv_sqrt_d = 0.044194173824159216f;  // 1/sqrt(512)

    // persistent register weights: row tid, cols k*64..k*64+63
    float4 w1r[16], w2r[16];
    {
        const float4* Wh = (const float4*)(W_h + (size_t)tid * DIM + k * SLICE);
        const float4* Ww = (const float4*)(W_write + (size_t)tid * DIM + k * SLICE);
#pragma unroll
        for (int j = 0; j < 16; ++j) { w1r[j] = Wh[j]; w2r[j] = Ww[j]; }
    }

    if (tid == 0) deadflag = 0;
    {   // tape init: transposed store
        const int n = tid >> 4, c4 = tid & 15;
        float4 tv = *(const float4*)(h_tape0 +
            ((size_t)(b * NSLOTS + n)) * DIM + k * SLICE + 4 * c4);
        tape_t[4 * c4 + 0][n] = tv.x;
        tape_t[4 * c4 + 1][n] = tv.y;
        tape_t[4 * c4 + 2][n] = tv.z;
        tape_t[4 * c4 + 3][n] = tv.w;
    }
    if (tid < SLICE) {
        wkF[tid] = h_work0[b * DIM + k * SLICE + tid];
        wvF[tid] = 0.f;
        m1F[tid] = 0.f;
    }
    __syncthreads();

    float* hseq_b = out + (size_t)b * SEQT * DIM;
    unsigned long long* pM = partsM + (size_t)b * KSPLIT * DIM;
    unsigned long long* pA = partsA + (size_t)b * KSPLIT * 33;
    int* tagA_b = tagA + b * 32;
    int* tagM_b = tagM + b * 32;

    // ---- prologue: matvec partials on work_0 -> EX-M tag 1 ----
    {
        const float4* wk4 = (const float4*)wkF;
        float m1 = 0.f, m2 = 0.f;
#pragma unroll
        for (int j = 0; j < 16; ++j) {
            float4 wv = wk4[j];
            m1 = fmaf(w1r[j].x, wv.x, m1); m1 = fmaf(w1r[j].y, wv.y, m1);
            m1 = fmaf(w1r[j].z, wv.z, m1); m1 = fmaf(w1r[j].w, wv.w, m1);
            m2 = fmaf(w2r[j].x, wv.x, m2); m2 = fmaf(w2r[j].y, wv.y, m2);
            m2 = fmaf(w2r[j].z, wv.z, m2); m2 = fmaf(w2r[j].w, wv.w, m2);
        }
        f2u v; v.f = make_float2(m1, m2);
        __hip_atomic_store(&pM[k * DIM + tid], v.u, __ATOMIC_RELAXED,
                           SCOPE_AGENT);
        asm volatile("s_waitcnt vmcnt(0)" ::: "memory");
        __syncthreads();
        if (tid == 0)
            __hip_atomic_store(&tagM_b[k], 1, __ATOMIC_RELAXED, SCOPE_AGENT);
        if (tid < 64) {
            poll8(tagM_b, 1, &deadflag, tid);
            float a1 = 0.f, a2 = 0.f;
#pragma unroll
            for (int j = 0; j < KSPLIT; ++j) {
                f2u v2;
                v2.u = __hip_atomic_load(&pM[j * DIM + k * SLICE + tid],
                                         __ATOMIC_RELAXED, SCOPE_AGENT);
                a1 += v2.f.x; a2 += v2.f.y;
            }
            m1F[tid] = a1;   // (W_h @ work_0)[own]
            wvF[tid] = a2;   // (W_write @ work_0)[own] — dead at t=0 (beta=0)
            asm volatile("s_waitcnt lgkmcnt(0)" ::: "memory");
        }
        // no barrier: only wave 0 reads wvF next (same wave); m1F read by
        // all happens after barrier A below.
    }

    for (int t = 0; t < SEQT; ++t) {
        // x(t) prefetch (waves 1-7 issue early; wave 0 issues after its
        // EX-A publish so the vmcnt drain doesn't wait on it)
        float xv = 0.f;
        if (tid >= 64 && (tid & 7) == 0)
            xv = hseq_b[(size_t)t * DIM + k * SLICE + (tid >> 3)];

        // ---- wave 0: EX-A partials + publish + tag + poll + entmax ----
        if (tid < 64) {
            const int s2 = tid >> 1, h = tid & 1;   // slot, col-half
            float up = 0.f, vp = 0.f, sp = 0.f;
#pragma unroll
            for (int m = 0; m < 8; ++m) {
                const int c0 = 32 * h + 4 * m;
                float4 wv = *(const float4*)&wvF[c0];
                float4 wk = *(const float4*)&wkF[c0];
                float t0 = tape_t[c0 + 0][s2], t1 = tape_t[c0 + 1][s2];
                float t2 = tape_t[c0 + 2][s2], t3 = tape_t[c0 + 3][s2];
                up = fmaf(t0, wv.x, up); up = fmaf(t1, wv.y, up);
                up = fmaf(t2, wv.z, up); up = fmaf(t3, wv.w, up);
                vp = fmaf(t0, wk.x, vp); vp = fmaf(t1, wk.y, vp);
                vp = fmaf(t2, wk.z, vp); vp = fmaf(t3, wk.w, vp);
                sp = fmaf(wv.x, wk.x, sp); sp = fmaf(wv.y, wk.y, sp);
                sp = fmaf(wv.z, wk.z, sp); sp = fmaf(wv.w, wk.w, sp);
            }
            up += __shfl_down(up, 1, 2);
            vp += __shfl_down(vp, 1, 2);
            sp += __shfl_down(sp, 1, 2);
            if (h == 0) {
                f2u v; v.f = make_float2(up, vp);
                __hip_atomic_store(&pA[k * 33 + s2], v.u, __ATOMIC_RELAXED,
                                   SCOPE_AGENT);
            }
            if (tid == 0) {
                f2u v; v.f = make_float2(sp, 0.f);
                __hip_atomic_store(&pA[k * 33 + 32], v.u, __ATOMIC_RELAXED,
                                   SCOPE_AGENT);
            }
            asm volatile("s_waitcnt vmcnt(0)" ::: "memory");
            if (tid == 0)
                __hip_atomic_store(&tagA_b[k], t + 1, __ATOMIC_RELAXED,
                                   SCOPE_AGENT);
            if ((tid & 7) == 0)   // wave 0's x slice, issued under the poll
                xv = hseq_b[(size_t)t * DIM + k * SLICE + (tid >> 3)];
            poll8(tagA_b, t + 1, &deadflag, tid);
            float uu = 0.f, vv = 0.f;
            if (tid < 33) {
#pragma unroll
                for (int j = 0; j < KSPLIT; ++j) {
                    f2u v2;
                    v2.u = __hip_atomic_load(&pA[j * 33 + tid],
                                             __ATOMIC_RELAXED, SCOPE_AGENT);
                    uu += v2.f.x; vv += v2.f.y;
                }
            }
            float sfull = __shfl(uu, 32, 64);
            float beta = 0.f;
            if (t > 0) beta = entmax64(uu * inv_sqrt_d, tid);
            float rr = ((1.0f - beta) * vv + beta * sfull) * inv_sqrt_d;
            float alpha = entmax64(rr, tid);
            if (tid < 32) probBA[tid] = make_float2(beta, alpha);
        }
        __syncthreads();   // A: probBA + m1F visible to all

        // ---- fused tape update + readv + tanh ----
        {
            const int c = tid >> 3, j = tid & 7;
            float wvc = wvF[c];
            float racc = 0.f;
#pragma unroll
            for (int i = 0; i < 4; ++i) {
                int n = 4 * j + i;
                float2 ba = probBA[n];
                float tv = tape_t[c][n];
                tv = tv * (1.0f - ba.x) + ba.x * wvc;
                tape_t[c][n] = tv;
                racc = fmaf(ba.y, tv, racc);
            }
            racc += __shfl_down(racc, 4, 8);
            racc += __shfl_down(racc, 2, 8);
            racc += __shfl_down(racc, 1, 8);
            if (j == 0) {
                float wn = tanhf(m1F[c] + xv + racc);
                wkF[c] = wn;
                hseq_b[(size_t)t * DIM + k * SLICE + c] = wn;
            }
        }
        __syncthreads();   // B: wkF = work(t+1) visible

        // ---- matvec partials on work(t+1); publish EX-M ----
        {
            const float4* wk4 = (const float4*)wkF;
            float m1 = 0.f, m2 = 0.f;
#pragma unroll
            for (int j = 0; j < 16; ++j) {
                float4 wv = wk4[j];
                m1 = fmaf(w1r[j].x, wv.x, m1); m1 = fmaf(w1r[j].y, wv.y, m1);
                m1 = fmaf(w1r[j].z, wv.z, m1); m1 = fmaf(w1r[j].w, wv.w, m1);
                m2 = fmaf(w2r[j].x, wv.x, m2); m2 = fmaf(w2r[j].y, wv.y, m2);
                m2 = fmaf(w2r[j].z, wv.z, m2); m2 = fmaf(w2r[j].w, wv.w, m2);
            }
            f2u v; v.f = make_float2(m1, m2);
            __hip_atomic_store(&pM[k * DIM + tid], v.u, __ATOMIC_RELAXED,
                               SCOPE_AGENT);
        }
        asm volatile("s_waitcnt vmcnt(0)" ::: "memory");
        __syncthreads();   // C: all EX-M stores drained
        if (tid == 0)
            __hip_atomic_store(&tagM_b[k], t + 2, __ATOMIC_RELAXED,
                               SCOPE_AGENT);
        if (tid < 64) {
            poll8(tagM_b, t + 2, &deadflag, tid);
            float a1 = 0.f, a2 = 0.f;
#pragma unroll
            for (int j = 0; j < KSPLIT; ++j) {
                f2u v2;
                v2.u = __hip_atomic_load(&pM[j * DIM + k * SLICE + tid],
                                         __ATOMIC_RELAXED, SCOPE_AGENT);
                a1 += v2.f.x; a2 += v2.f.y;
            }
            m1F[tid] = a1;   // (W_h @ work_{t+1})[own]
            wvF[tid] = a2;   // wvec(t) = (W_write @ work_{t+1})[own]
            asm volatile("s_waitcnt lgkmcnt(0)" ::: "memory");
        }
        // no barrier: next-iter consumers of m1F wait at barrier A; wvF/wkF
        // consumed first by wave 0 itself.
    }

    // ---- epilogue: beta(T-1) and final tape update ----
    if (tid < 64) {
        const int s2 = tid >> 1, h = tid & 1;
        float up = 0.f;
#pragma unroll
        for (int m = 0; m < 8; ++m) {
            const int c0 = 32 * h + 4 * m;
            float4 wv = *(const float4*)&wvF[c0];
            up = fmaf(tape_t[c0 + 0][s2], wv.x, up);
            up = fmaf(tape_t[c0 + 1][s2], wv.y, up);
            up = fmaf(tape_t[c0 + 2][s2], wv.z, up);
            up = fmaf(tape_t[c0 + 3][s2], wv.w, up);
        }
        up += __shfl_down(up, 1, 2);
        if (h == 0) {
            f2u v; v.f = make_float2(up, 0.f);
            __hip_atomic_store(&pA[k * 33 + s2], v.u, __ATOMIC_RELAXED,
                               SCOPE_AGENT);
        }
        asm volatile("s_waitcnt vmcnt(0)" ::: "memory");
        if (tid == 0)
            __hip_atomic_store(&tagA_b[k], SEQT + 1, __ATOMIC_RELAXED,
                               SCOPE_AGENT);
        poll8(tagA_b, SEQT + 1, &deadflag, tid);
        float uu = 0.f;
        if (tid < 32) {
#pragma unroll
            for (int j = 0; j < KSPLIT; ++j) {
                f2u v2;
                v2.u = __hip_atomic_load(&pA[j * 33 + tid], __ATOMIC_RELAXED,
                                         SCOPE_AGENT);
                uu += v2.f.x;
            }
        }
        float beta = entmax64(uu * inv_sqrt_d, tid);
        if (tid < 32) probBA[tid] = make_float2(beta, 0.f);
    }
    __syncthreads();
    {
        const int c = tid >> 3, j = tid & 7;
        float wvc = wvF[c];
#pragma unroll
        for (int i = 0; i < 4; ++i) {
            int n = 4 * j + i;
            float bb = probBA[n].x;
            float tv = tape_t[c][n];
            tape_t[c][n] = tv * (1.0f - bb) + bb * wvc;
        }
    }
    __syncthreads();

    // outputs: tape_final own col-slice + h_last own slice
    {
        const int n = tid >> 4, c4 = tid & 15;
        float4 tv = {tape_t[4 * c4 + 0][n], tape_t[4 * c4 + 1][n],
                     tape_t[4 * c4 + 2][n], tape_t[4 * c4 + 3][n]};
        *(float4*)(out + (size_t)BATCH * SEQT * DIM +
                   ((size_t)(b * NSLOTS + n)) * DIM + k * SLICE + 4 * c4) = tv;
    }
    if (tid < SLICE)
        out[(size_t)BATCH * SEQT * DIM + (size_t)BATCH * NSLOTS * DIM +
            (size_t)b * DIM + k * SLICE + tid] = wkF[tid];
}

// ============================================================================
extern "C" void kernel_launch(void* const* d_in, const int* in_sizes, int n_in,
                              void* d_out, int out_size, void* d_ws,
                              size_t ws_size, hipStream_t stream)
{
    const float* x_seq   = (const float*)d_in[0];
    const float* h_tape  = (const float*)d_in[1];
    const float* h_work  = (const float*)d_in[2];
    const float* W_h     = (const float*)d_in[3];
    const float* W_x     = (const float*)d_in[4];
    const float* b_h     = (const float*)d_in[5];
    const float* W_write = (const float*)d_in[6];
    float* out = (float*)d_out;

    unsigned long long* partsM = (unsigned long long*)d_ws;              // 1 MB
    unsigned long long* partsA = partsM + (size_t)BATCH * KSPLIT * DIM;  // 66 KB
    int* tagA = (int*)(partsA + (size_t)BATCH * KSPLIT * 33);            // 4 KB
    int* tagM = tagA + BATCH * 32;                                       // 4 KB

    hipMemsetAsync(tagA, 0, 2 * BATCH * 32 * sizeof(int), stream);

    dim3 g1((BATCH * SEQT) / 64, DIM / 64);
    xw_gemm_kernel<<<g1, 256, 0, stream>>>(x_seq, W_x, b_h, out);

    recurrent_kernel<<<BATCH * KSPLIT, TPB, 0, stream>>>(
        h_tape, h_work, W_h, W_write, out, partsM, partsA, tagA, tagM);
}